// Round 4
// baseline (264.418 us; speedup 1.0000x reference)
//
#include <hip/hip_runtime.h>
#include <math.h>

#define S 1024
#define RADIUS 512
#define NIMG 32   // 16 "output" images then 16 "target" images
#define PBX 129   // pass-B blocks per image (u-groups of 4)

// ---------------------------------------------------------------------------
// Complex helpers
// ---------------------------------------------------------------------------
__device__ __forceinline__ float2 cmul(float2 a, float2 b) {
    return make_float2(a.x * b.x - a.y * b.y, a.x * b.y + a.y * b.x);
}
__device__ __forceinline__ float2 cadd(float2 a, float2 b) { return make_float2(a.x + b.x, a.y + b.y); }
__device__ __forceinline__ float2 csub(float2 a, float2 b) { return make_float2(a.x - b.x, a.y - b.y); }

// W_16^k, k=0..7
__device__ const float2 C16[8] = {
    {1.0f, 0.0f},
    {0.92387953251128674f, -0.38268343236508978f},
    {0.70710678118654757f, -0.70710678118654746f},
    {0.38268343236508984f, -0.92387953251128674f},
    {0.0f, -1.0f},
    {-0.38268343236508973f, -0.92387953251128674f},
    {-0.70710678118654746f, -0.70710678118654757f},
    {-0.92387953251128663f, -0.38268343236508989f},
};
// W_8^k, k=0..3
__device__ const float2 C8T[4] = {
    {1.0f, 0.0f},
    {0.70710678118654757f, -0.70710678118654746f},
    {0.0f, -1.0f},
    {-0.70710678118654746f, -0.70710678118654757f},
};
// W_128^{bitrev3(m)} for m=0..7 (combine-step twiddles)
__device__ const float2 C128R[8] = {
    {1.0f, 0.0f},
    {0.98078528040323044f, -0.19509032201612825f},   // W128^4
    {0.99518472667219693f, -0.09801714032956060f},   // W128^2
    {0.95694033573220886f, -0.29028467725446233f},   // W128^6
    {0.99879545620517241f, -0.04906767432741801f},   // W128^1
    {0.97003125319454397f, -0.24298017990326390f},   // W128^5
    {0.98917650996478101f, -0.14673047445536175f},   // W128^3
    {0.94154406518302081f, -0.33688985339222005f},   // W128^7
};

// 4 radix-2 DIF stages over 16 register elements (pass A)
__device__ __forceinline__ void fft16(float2 r[16], float2 T) {
    float2 tc[8];
    #pragma unroll
    for (int u = 0; u < 8; ++u) tc[u] = cmul(T, C16[u]);
    #pragma unroll
    for (int u = 0; u < 8; ++u) {
        float2 a = r[u], b = r[u + 8];
        r[u] = cadd(a, b);
        r[u + 8] = cmul(csub(a, b), tc[u]);
    }
    T = cmul(T, T);
    #pragma unroll
    for (int u = 0; u < 4; ++u) tc[u] = cmul(T, C16[2 * u]);
    #pragma unroll
    for (int g = 0; g < 2; ++g)
        #pragma unroll
        for (int u = 0; u < 4; ++u) {
            int lo = g * 8 + u;
            float2 a = r[lo], b = r[lo + 4];
            r[lo] = cadd(a, b);
            r[lo + 4] = cmul(csub(a, b), tc[u]);
        }
    T = cmul(T, T);
    #pragma unroll
    for (int u = 0; u < 2; ++u) tc[u] = cmul(T, C16[4 * u]);
    #pragma unroll
    for (int g = 0; g < 4; ++g)
        #pragma unroll
        for (int u = 0; u < 2; ++u) {
            int lo = g * 4 + u;
            float2 a = r[lo], b = r[lo + 2];
            r[lo] = cadd(a, b);
            r[lo + 2] = cmul(csub(a, b), tc[u]);
        }
    T = cmul(T, T);
    #pragma unroll
    for (int g = 0; g < 8; ++g) {
        int lo = g * 2;
        float2 a = r[lo], b = r[lo + 1];
        r[lo] = cadd(a, b);
        r[lo + 1] = cmul(csub(a, b), T);
    }
}

// 3 radix-2 DIF stages over TWO independent 8-element sets (shared twiddles).
__device__ __forceinline__ void fft8x2(float2 a[8], float2 b[8], float2 T) {
    float2 tc[4];
    #pragma unroll
    for (int u = 0; u < 4; ++u) tc[u] = cmul(T, C8T[u]);
    #pragma unroll
    for (int u = 0; u < 4; ++u) {
        float2 xa = a[u], ya = a[u + 4];
        a[u] = cadd(xa, ya);
        a[u + 4] = cmul(csub(xa, ya), tc[u]);
        float2 xb = b[u], yb = b[u + 4];
        b[u] = cadd(xb, yb);
        b[u + 4] = cmul(csub(xb, yb), tc[u]);
    }
    T = cmul(T, T);
    #pragma unroll
    for (int u = 0; u < 2; ++u) tc[u] = cmul(T, C8T[2 * u]);
    #pragma unroll
    for (int g = 0; g < 2; ++g)
        #pragma unroll
        for (int u = 0; u < 2; ++u) {
            int lo = g * 4 + u;
            float2 xa = a[lo], ya = a[lo + 2];
            a[lo] = cadd(xa, ya);
            a[lo + 2] = cmul(csub(xa, ya), tc[u]);
            float2 xb = b[lo], yb = b[lo + 2];
            b[lo] = cadd(xb, yb);
            b[lo + 2] = cmul(csub(xb, yb), tc[u]);
        }
    T = cmul(T, T);
    #pragma unroll
    for (int g = 0; g < 4; ++g) {
        int lo = g * 2;
        float2 xa = a[lo], ya = a[lo + 1];
        a[lo] = cadd(xa, ya);
        a[lo + 1] = cmul(csub(xa, ya), T);
        float2 xb = b[lo], yb = b[lo + 1];
        b[lo] = cadd(xb, yb);
        b[lo + 1] = cmul(csub(xb, yb), T);
    }
}

// Last 2 DIF stages (1024-pt, pass A): shuffles across c = tau&3
__device__ __forceinline__ void fft_last2(float2 r[16], int c) {
    #pragma unroll
    for (int m = 0; m < 16; ++m) {
        float vx = __shfl_xor(r[m].x, 2, 64);
        float vy = __shfl_xor(r[m].y, 2, 64);
        if (c & 2) {
            float dx = vx - r[m].x, dy = vy - r[m].y;
            if (c & 1) { r[m].x = dy; r[m].y = -dx; }
            else       { r[m].x = dx; r[m].y = dy; }
        } else {
            r[m].x += vx; r[m].y += vy;
        }
    }
    #pragma unroll
    for (int m = 0; m < 16; ++m) {
        float vx = __shfl_xor(r[m].x, 1, 64);
        float vy = __shfl_xor(r[m].y, 1, 64);
        if (c & 1) { r[m].x = vx - r[m].x; r[m].y = vy - r[m].y; }
        else       { r[m].x += vx; r[m].y += vy; }
    }
}

// Last 3 DIF stages (512-pt) for two independent sets, interleaved.
__device__ __forceinline__ void fft_last3x2(float2 a[8], float2 b[8], int lam) {
    const float R2 = 0.70710678118654757f;
    int k = lam & 3;
    float2 w8;
    w8.x = (k == 0) ? 1.0f : ((k == 1) ? R2 : ((k == 2) ? 0.0f : -R2));
    w8.y = (k == 0) ? 0.0f : ((k == 2) ? -1.0f : -R2);
    #pragma unroll
    for (int m = 0; m < 8; ++m) {
        float ax = __shfl_xor(a[m].x, 4, 64);
        float ay = __shfl_xor(a[m].y, 4, 64);
        float bx = __shfl_xor(b[m].x, 4, 64);
        float by = __shfl_xor(b[m].y, 4, 64);
        if (lam & 4) {
            a[m] = cmul(make_float2(ax - a[m].x, ay - a[m].y), w8);
            b[m] = cmul(make_float2(bx - b[m].x, by - b[m].y), w8);
        } else {
            a[m].x += ax; a[m].y += ay;
            b[m].x += bx; b[m].y += by;
        }
    }
    #pragma unroll
    for (int m = 0; m < 8; ++m) {
        float ax = __shfl_xor(a[m].x, 2, 64);
        float ay = __shfl_xor(a[m].y, 2, 64);
        float bx = __shfl_xor(b[m].x, 2, 64);
        float by = __shfl_xor(b[m].y, 2, 64);
        if (lam & 2) {
            float dax = ax - a[m].x, day = ay - a[m].y;
            float dbx = bx - b[m].x, dby = by - b[m].y;
            if (lam & 1) { a[m].x = day; a[m].y = -dax; b[m].x = dby; b[m].y = -dbx; }
            else         { a[m].x = dax; a[m].y = day;  b[m].x = dbx; b[m].y = dby; }
        } else {
            a[m].x += ax; a[m].y += ay;
            b[m].x += bx; b[m].y += by;
        }
    }
    #pragma unroll
    for (int m = 0; m < 8; ++m) {
        float ax = __shfl_xor(a[m].x, 1, 64);
        float ay = __shfl_xor(a[m].y, 1, 64);
        float bx = __shfl_xor(b[m].x, 1, 64);
        float by = __shfl_xor(b[m].y, 1, 64);
        if (lam & 1) {
            a[m].x = ax - a[m].x; a[m].y = ay - a[m].y;
            b[m].x = bx - b[m].x; b[m].y = by - b[m].y;
        } else {
            a[m].x += ax; a[m].y += ay;
            b[m].x += bx; b[m].y += by;
        }
    }
}

// Swizzled LDS addr for 1024-pt transpose (pass A)
__device__ __forceinline__ int A1x(int n) {
    int j = n >> 6;
    return (n & ~63) | ((n & 63) ^ (j << 2));
}

// Dual 512-pt FFT, fully interleaved. bufA = wave-private 1024-slot region;
// A uses [0..511], B uses [512..1023]. Output position p = 64*(tau>>3)+8m+(tau&7),
// freq t = bitrev9(p).
__device__ __forceinline__ void fft512x2(float2 ra[8], float2 rb[8], float2* bufA,
                                         int tau, float2 T1, float2 T2) {
    float2* bufB = bufA + 512;
    fft8x2(ra, rb, T1);
    #pragma unroll
    for (int j = 0; j < 8; ++j) bufA[(j << 6) | (tau ^ (j << 3))] = ra[j];
    #pragma unroll
    for (int j = 0; j < 8; ++j) bufB[(j << 6) | (tau ^ (j << 3))] = rb[j];
    const int b3 = tau >> 3, lam = tau & 7;
    #pragma unroll
    for (int m = 0; m < 8; ++m) ra[m] = bufA[(b3 << 6) | (((m ^ b3) << 3) + lam)];
    #pragma unroll
    for (int m = 0; m < 8; ++m) rb[m] = bufB[(b3 << 6) | (((m ^ b3) << 3) + lam)];
    fft8x2(ra, rb, T2);
    fft_last3x2(ra, rb, lam);
}

__device__ __forceinline__ int bitrev3(int x) {
    return ((x & 1) << 2) | (x & 2) | ((x >> 2) & 1);
}

// ---------------------------------------------------------------------------
// Pass A: packed row-pair FFTs (unchanged from round 3 — validated, ~73% HBM).
// ---------------------------------------------------------------------------
__global__ __launch_bounds__(512)
void fft_rows(const float* __restrict__ outp, const float* __restrict__ tgtp,
              float2* __restrict__ WpT, int imgBase) {
    __shared__ float2 buf[8 * 1024];
    const int t = threadIdx.x;
    const int w = t >> 6, tau = t & 63;
    const int yy = blockIdx.x * 8 + w;
    const int i = blockIdx.y, g = imgBase + i;
    const float* img = (g < 16 ? outp : tgtp) + (size_t)(g & 15) * S * S;
    const float* r0 = img + (size_t)(2 * yy) * S;
    const float* r1 = r0 + S;

    float2 r[16];
    #pragma unroll
    for (int j = 0; j < 16; ++j) r[j] = make_float2(r0[64 * j + tau], r1[64 * j + tau]);

    float2 T;
    { float sv, cv; sincosf(-6.283185307179586f * (float)tau / 1024.0f, &sv, &cv); T = make_float2(cv, sv); }
    fft16(r, T);

    float2* mybuf = buf + (w << 10);
    #pragma unroll
    for (int j = 0; j < 16; ++j) mybuf[A1x(64 * j + tau)] = r[j];
    const int b = tau >> 2, c = tau & 3;
    #pragma unroll
    for (int m = 0; m < 16; ++m) r[m] = mybuf[(b << 6) + 4 * (m ^ b) + c];

    { float sv, cv; sincosf(-6.283185307179586f * (float)c / 64.0f, &sv, &cv); T = make_float2(cv, sv); }
    fft16(r, T);
    fft_last2(r, c);

    #pragma unroll
    for (int m = 0; m < 16; ++m) {
        int n = (b << 6) + 4 * m + c;
        int k = (int)(__brev((unsigned)n) >> 22);
        mybuf[k ^ (w << 1)] = r[m];
    }
    __syncthreads();

    const int yy0 = blockIdx.x * 8;
    float2* dst = WpT + (size_t)i * 512 * 1024;
    #pragma unroll
    for (int q = 0; q < 16; ++q) {
        int idx = q * 512 + t;
        int uu = idx >> 3, wv = idx & 7;
        float2 val = buf[(wv << 10) | (uu ^ (wv << 1))];
        dst[(size_t)uu * 512 + yy0 + wv] = val;
    }
}

// ---------------------------------------------------------------------------
// Pass B: Hermitian split + DUAL interleaved 512-pt FFTs + combine + bin.
// Block = 4 waves = 4 u-values; per-block histogram -> partials (no global atomics).
// ---------------------------------------------------------------------------
__global__ __launch_bounds__(256)
void fft_cols_bin(const float2* __restrict__ WpT, float* __restrict__ partial, int imgBase) {
    __shared__ float2 tbuf[4 * 1024];   // 32 KB: 1024-slot (A|B) region per wave
    __shared__ float bins[RADIUS + 1];
    const int t = threadIdx.x;
    const int w = t >> 6, tau = t & 63;
    const int i = blockIdx.y, g = imgBase + i;
    const int u = blockIdx.x * 4 + w;            // 0..515

    for (int j = t; j <= RADIUS; j += 256) bins[j] = 0.0f;
    __syncthreads();

    if (u <= 512) {
        const float2* Wimg = WpT + (size_t)i * 512 * 1024;
        const int mu = (1024 - u) & 1023;
        const float2* rowA = Wimg + (size_t)u * 512;
        const float2* rowM = Wimg + (size_t)mu * 512;

        float2 X0[8], X1[8];
        #pragma unroll
        for (int j = 0; j < 8; ++j) {
            float2 A = rowA[64 * j + tau];
            float2 M = rowM[64 * j + tau];
            X0[j] = make_float2(0.5f * (A.x + M.x), 0.5f * (A.y - M.y));
            X1[j] = make_float2(0.5f * (A.y + M.y), 0.5f * (M.x - A.x));
        }

        float2 T1, T2;
        { float sv, cv; sincosf(-6.283185307179586f * (float)tau / 512.0f, &sv, &cv); T1 = make_float2(cv, sv); }
        const int lam = tau & 7, b3 = tau >> 3;
        { float sv, cv; sincosf(-6.283185307179586f * (float)lam / 64.0f, &sv, &cv); T2 = make_float2(cv, sv); }

        fft512x2(X0, X1, tbuf + (w << 10), tau, T1, T2);

        const int rlam = bitrev3(lam), rb3 = bitrev3(b3);
        float2 Tc;
        { float sv, cv; sincosf(-6.283185307179586f * (float)(64 * rlam + rb3) / 1024.0f, &sv, &cv); Tc = make_float2(cv, sv); }

        const float cu = (u < 512) ? (u + 0.5f) : (u - 1023.5f);
        const float cum = 0.5f - (float)u;            // mirror column coordinate
        const bool dbl = (u >= 1 && u <= 511);

        #pragma unroll
        for (int m = 0; m < 8; ++m) {
            float2 Wv = cmul(Tc, C128R[m]);
            float2 w1 = cmul(Wv, X1[m]);
            float2 Gp = cadd(X0[m], w1);              // v = tf
            float2 Gm = csub(X0[m], w1);              // v = tf + 512
            int tf = 64 * rlam + 8 * bitrev3(m) + rb3;
            float p1 = Gp.x * Gp.x + Gp.y * Gp.y;
            float p2 = Gm.x * Gm.x + Gm.y * Gm.y;

            float cv1 = tf + 0.5f;
            float cv2 = tf - 511.5f;
            float d1 = sqrtf(cu * cu + cv1 * cv1);
            float d2 = sqrtf(cu * cu + cv2 * cv2);
            if (d1 < (float)RADIUS) atomicAdd(&bins[(int)d1], p1);
            if (d2 < (float)RADIUS) atomicAdd(&bins[(int)d2], p2);
            if (dbl) {
                int v1m = (1024 - tf) & 1023;
                int v2m = 512 - tf;
                float cv1m = (v1m < 512) ? (v1m + 0.5f) : (v1m - 1023.5f);
                float cv2m = (v2m < 512) ? (v2m + 0.5f) : (v2m - 1023.5f);
                float d1m = sqrtf(cum * cum + cv1m * cv1m);
                float d2m = sqrtf(cum * cum + cv2m * cv2m);
                if (d1m < (float)RADIUS) atomicAdd(&bins[(int)d1m], p1);
                if (d2m < (float)RADIUS) atomicAdd(&bins[(int)d2m], p2);
            }
        }
    }
    __syncthreads();
    // per-block partial histogram; every slot written every call (re-poison safe)
    float* dst = partial + ((size_t)g * PBX + blockIdx.x) * RADIUS;
    for (int j = t; j < RADIUS; j += 256) dst[j] = bins[j];
}

// ---------------------------------------------------------------------------
// Fold partials -> rad  (rad[g][j] = sum over PBX blocks)
// ---------------------------------------------------------------------------
__global__ __launch_bounds__(256)
void reduce_partials(const float* __restrict__ partial, float* __restrict__ rad) {
    int idx = blockIdx.x * 256 + threadIdx.x;    // 0 .. NIMG*RADIUS-1
    if (idx >= NIMG * RADIUS) return;
    int g = idx >> 9, j = idx & (RADIUS - 1);
    const float* p = partial + (size_t)g * PBX * RADIUS + j;
    float s = 0.0f;
    for (int b = 0; b < PBX; ++b) s += p[(size_t)b * RADIUS];
    rad[idx] = s;
}

// ---------------------------------------------------------------------------
// Final: loss = mean(|rad_out - rad_tgt|) / S^2
// ---------------------------------------------------------------------------
__global__ __launch_bounds__(256)
void final_loss(const float* __restrict__ rad, float* __restrict__ out) {
    __shared__ float red[256];
    const int t = threadIdx.x;
    float acc = 0.0f;
    for (int i = t; i < 16 * RADIUS; i += 256) {
        int bb = i >> 9;
        int rr = i & (RADIUS - 1);
        float o = rad[(size_t)bb * RADIUS + rr];
        float gg = rad[(size_t)(bb + 16) * RADIUS + rr];
        acc += fabsf(o - gg);
    }
    red[t] = acc;
    __syncthreads();
    for (int off = 128; off > 0; off >>= 1) {
        if (t < off) red[t] += red[t + off];
        __syncthreads();
    }
    if (t == 0) {
        out[0] = red[0] / ((float)S * (float)S) / (16.0f * (float)RADIUS);
    }
}

extern "C" void kernel_launch(void* const* d_in, const int* in_sizes, int n_in,
                              void* d_out, int out_size, void* d_ws, size_t ws_size,
                              hipStream_t stream) {
    const float* outp = (const float*)d_in[0];
    const float* tgtp = (const float*)d_in[1];
    float* dout = (float*)d_out;

    char* ws = (char*)d_ws;
    float* rad = (float*)ws;                                       // 64 KB
    const size_t partBytes = (size_t)NIMG * PBX * RADIUS * sizeof(float);  // 8.45 MB
    float* partial = (float*)(ws + 65536);
    float2* WpT = (float2*)(ws + 65536 + partBytes);
    const size_t perImg = (size_t)512 * 1024 * sizeof(float2);     // 4 MB / image
    size_t used = 65536 + partBytes;
    size_t avail = (ws_size > used) ? (ws_size - used) : 0;
    int chunk = (int)(avail / perImg);
    if (chunk > NIMG) chunk = NIMG;
    if (chunk < 1) chunk = 1;

    for (int base = 0; base < NIMG; base += chunk) {
        int c = (NIMG - base < chunk) ? (NIMG - base) : chunk;
        fft_rows<<<dim3(64, c), 512, 0, stream>>>(outp, tgtp, WpT, base);
        fft_cols_bin<<<dim3(PBX, c), 256, 0, stream>>>(WpT, partial, base);
    }

    reduce_partials<<<(NIMG * RADIUS + 255) / 256, 256, 0, stream>>>(partial, rad);
    final_loss<<<1, 256, 0, stream>>>(rad, dout);
}